// Round 6
// baseline (215.903 us; speedup 1.0000x reference)
//
#include <hip/hip_runtime.h>
#include <stdint.h>

// ListwiseLoss: B=524288 rows, H=32.
//   kl_row = sum_valid e_i*(s_i - g_i) / se,  e = exp(s),
//   g_i = s of the (rank_i)-th valid element in index order
// (max-sub and log(se) cancel between the KL sums; eps dropped — validated
//  rounds 1-12, absmax 0.0).
//
// Round-13: WAVE-COOPERATIVE rows (one row per 32-lane half, 2 rows/wave/iter).
// Why: rounds 8-12 proved the per-thread-sort structure is stuck at 77-95us
// regardless of staging scheme: VALU-busy ~6.4k cyc/wave vs ~25k wall, warm
// (L3) == cold, spill-free and conflict-free variants identical, and even a
// fully glds-prefetched variant (R11) kept a ~21k cyc/tile unexplained stall.
// Common factor: a 16-20KB fully-unrolled body (register sort forces unroll)
// + lockstep waves. This round eliminates the structure itself:
//  * element e of row r lives in lane 32*(r&1)+e  ->  rank/score/mask loads
//    are PERFECTLY coalesced with NO LDS staging and NO transpose at all
//    (addr = 64*pair + lane).
//  * rank ordering via bitonic sort ACROSS lanes (__shfl_xor, j<=16 stays
//    inside each half): 15 stages x ~4 instrs, compact loopable body (~2KB).
//  * pred-order pairing g via ONE ds_permute push: slot = prefix-popcount
//    position (ballot+mbcnt). No compaction scatter, no second sort.
//  * ~30 VGPRs, no LDS capacity -> 2048 blocks x 4 waves = 8 waves/SIMD,
//    ALL 8192 waves resident (zero turnover), 32 iters/wave, 1-deep load
//    prefetch. Lockstep + per-wave overhead amortized by the iter loop.
// Sort word: w = (key16<<16)|bf16(s); key16 = valid?(r<<5)|e5 : 0x4000|e5
// (unique; col tiebreak matches reference's stable argsort).

#define H 32
#define BLK 256
#define WPB 4

__global__ __launch_bounds__(BLK) void listwise_kernel(
    const float* __restrict__ scores,
    const int* __restrict__ rankings,
    const unsigned char* __restrict__ mask_u8,
    float* __restrict__ part_kl,
    float* __restrict__ part_cnt,
    int nrows, int ipw)
{
    __shared__ float s_kl[WPB], s_cnt[WPB];

    const int tid  = threadIdx.x;
    const int lane = tid & 63;
    const int wid  = tid >> 6;
    const int e5   = lane & 31;          // element within row
    const int h    = lane >> 5;          // which row of the pair

    const long long wave_g = (long long)blockIdx.x * WPB + wid;
    const long long tpairs = ((long long)nrows + 1) >> 1;
    const long long pbase  = wave_g * ipw;
    const long long pend   = (pbase + ipw < tpairs) ? (pbase + ipw) : tpairs;

    // mask dtype detect (bool=1B vs int32=4B); wave-uniform branch
    unsigned char probe = mask_u8[lane];
    const bool mask_is_i32 =
        (__ballot(((lane & 3) != 0) && (probe != 0)) == 0ull);

    float kl_acc = 0.0f, cnt_acc = 0.0f;

    if (pbase < pend) {
        const size_t maxidx = (size_t)nrows * H - 1;

        // ---- prefetch iter 0 (clamped addressing; validity re-checked) ----
        size_t b = (size_t)pbase * 64 + lane;
        if (b > maxidx) b = maxidx;
        int      rv = rankings[b];
        float    sv = scores[b];
        uint32_t mv = mask_is_i32 ? (uint32_t)((const int*)mask_u8)[b]
                                  : (uint32_t)mask_u8[b];

        for (long long p = pbase; p < pend; ++p) {
            // ---- issue next-iter loads (1-deep prefetch, 3 regs) ----
            const long long pn = (p + 1 < pend) ? (p + 1) : p;
            size_t bn = (size_t)pn * 64 + lane;
            if (bn > maxidx) bn = maxidx;
            const int      rvn = rankings[bn];
            const float    svn = scores[bn];
            const uint32_t mvn = mask_is_i32
                ? (uint32_t)((const int*)mask_u8)[bn]
                : (uint32_t)mask_u8[bn];

            // ---- build sort word + validity ----
            const int  row   = (int)(2 * p) + h;
            const bool valid = (row < nrows) && (mv != 0u) && (rv > 0);
            const uint32_t b16 = (__float_as_uint(sv) + 0x8000u) >> 16;
            const uint32_t key = valid ? (((uint32_t)rv << 5) | (uint32_t)e5)
                                       : (0x4000u | (uint32_t)e5);
            uint32_t w = (key << 16) | b16;
            const float gsrc = __uint_as_float(b16 << 16); // bf16'd score f32

            // ---- idx-order position q via ballot + mbcnt; park invalids ----
            const unsigned long long vm = __ballot(valid);
            const uint32_t mb = __builtin_amdgcn_mbcnt_hi(
                (uint32_t)(vm >> 32),
                __builtin_amdgcn_mbcnt_lo((uint32_t)vm, 0u));
            const int plo = __builtin_popcountll(vm & 0xffffffffull);
            const int phi = __builtin_popcountll(vm >> 32);
            const int q   = (int)mb - (h ? plo : 0);      // #valid below, in half
            const int nvh = h ? phi : plo;                // row's valid count
            const int slot = (valid ? q : (nvh + (e5 - q))) + (h << 5);
            // push my (bf16'd) score to lane 'slot': lane p<nv ends up holding
            // the score of the idx-order-p valid element (= g source)
            const float gq = __uint_as_float(
                __builtin_amdgcn_ds_permute(slot << 2, (int)__float_as_uint(gsrc)));

            // ---- bitonic sort across each 32-lane half (ascending) ----
            // take_max = ((e5&j)==0) ^ ((e5&k)==0); lane-dependent but
            // iter-invariant -> LICM hoists the 15 masks out of the p-loop.
            #pragma unroll
            for (int k = 2; k <= 32; k <<= 1) {
                #pragma unroll
                for (int j = k >> 1; j > 0; j >>= 1) {
                    const uint32_t pw = (uint32_t)__shfl_xor((int)w, j);
                    const uint32_t mn = w < pw ? w : pw;
                    const uint32_t mx = w < pw ? pw : w;
                    const bool tm = (((e5 & j) == 0) != ((e5 & k) == 0));
                    w = tm ? mx : mn;
                }
            }

            // ---- KL terms: lane p holds rank-p element; gq holds idx-p s ----
            const bool  vld = (w < 0x40000000u);          // p < nvh
            const float sb  = __uint_as_float(w << 16);
            float e = __expf(sb);
            e = vld ? e : 0.0f;
            const float d = vld ? (sb - gq) : 0.0f;
            float se = e;
            float nm = e * d;
            #pragma unroll
            for (int j2 = 1; j2 <= 16; j2 <<= 1) {
                se += __shfl_xor(se, j2);
                nm += __shfl_xor(nm, j2);
            }
            const bool rok = (nvh > 1);
            const float contrib = rok ? __fdividef(nm, se) : 0.0f;
            kl_acc  += (e5 == 0) ? contrib : 0.0f;
            cnt_acc += (e5 == 0 && rok) ? 1.0f : 0.0f;

            rv = rvn; sv = svn; mv = mvn;
        }
    }

    // ---- combine the two half-rows of the wave, then block partial ----
    kl_acc  += __shfl_xor(kl_acc, 32);
    cnt_acc += __shfl_xor(cnt_acc, 32);
    if (lane == 0) { s_kl[wid] = kl_acc; s_cnt[wid] = cnt_acc; }
    __syncthreads();
    if (tid == 0) {
        part_kl[blockIdx.x]  = s_kl[0] + s_kl[1] + s_kl[2] + s_kl[3];
        part_cnt[blockIdx.x] = s_cnt[0] + s_cnt[1] + s_cnt[2] + s_cnt[3];
    }
}

__global__ __launch_bounds__(256) void finalize_kernel(
    const float* __restrict__ part_kl,
    const float* __restrict__ part_cnt,
    float* __restrict__ out, int nblk)
{
    float k = 0.0f, c = 0.0f;
    for (int i = threadIdx.x; i < nblk; i += 256) {
        k += part_kl[i];
        c += part_cnt[i];
    }
    #pragma unroll
    for (int m = 32; m >= 1; m >>= 1) {
        k += __shfl_xor(k, m);
        c += __shfl_xor(c, m);
    }
    __shared__ float sk[4], sc[4];
    const int wid = threadIdx.x >> 6;
    if ((threadIdx.x & 63) == 0) { sk[wid] = k; sc[wid] = c; }
    __syncthreads();
    if (threadIdx.x == 0) {
        float K = sk[0] + sk[1] + sk[2] + sk[3];
        float C = sc[0] + sc[1] + sc[2] + sc[3];
        if (C < 1.0f) C = 1.0f;
        out[0] = K / C;
    }
}

extern "C" void kernel_launch(void* const* d_in, const int* in_sizes, int n_in,
                              void* d_out, int out_size, void* d_ws, size_t ws_size,
                              hipStream_t stream) {
    const float* scores = (const float*)d_in[0];
    const int* rankings = (const int*)d_in[1];
    const unsigned char* mask = (const unsigned char*)d_in[2];
    float* out = (float*)d_out;

    const int total = in_sizes[0];                 // B*H = 16777216
    const int nrows = total / H;                   // 524288 rows
    const int blocks = 2048;                       // 8192 waves, all resident
    const long long tpairs = ((long long)nrows + 1) >> 1;       // 262144
    const long long waves = (long long)blocks * WPB;            // 8192
    int ipw = (int)((tpairs + waves - 1) / waves);              // 32
    if (ipw < 1) ipw = 1;

    float* part_kl  = (float*)d_ws;               // [0, blocks)
    float* part_cnt = (float*)d_ws + blocks;      // [blocks, 2*blocks)

    listwise_kernel<<<blocks, BLK, 0, stream>>>(
        scores, rankings, mask, part_kl, part_cnt, nrows, ipw);

    finalize_kernel<<<1, 256, 0, stream>>>(part_kl, part_cnt, out, blocks);
}

// Round 7
// 206.895 us; speedup vs baseline: 1.0435x; 1.0435x over previous
//
#include <hip/hip_runtime.h>
#include <stdint.h>

// ListwiseLoss: B=524288 rows, H=32.
//   kl_row = sum_valid e_i*(s_i - g_i) / se,  e = exp(s),
//   g_i = s of the (rank_i)-th valid element in index order
// (max-sub and log(se) cancel between the KL sums; eps dropped — validated
//  rounds 1-13, absmax 0.0).
//
// Round-14: PACKED cross-lane sort (4 rows/wave/iter) + DPP.
// R13's counters finally decomposed the wall: DS pipe ~72us busy (28 wave-DS
// ops per 2 rows: 15 sort shfl + permute + 12 reduce shfl) and VALU ~50us
// (full 15-stage network amortized over only 2 rows). Fixes, same structure:
//  * u16 sort keys (valid?(r<<5)|idx : 0x8000|idx, r<=32 -> 12 bits), TWO
//    rows packed per dword, compared with packed u16 min/max -> one network
//    sorts 4 rows (2 per 32-lane half).
//  * exchanges j=1,2 via DPP quad_perm (VALU, not DS): 9 of 15 exchanges
//    leave the DS pipe; j=4,8,16 remain shfl_xor (ds_swizzle).
//  * ALL reductions via DPP ladder row_shr:1/2/4/8 + row_bcast:15 (VALU,
//    zero DS); lanes 31/63 hold their half's sums.
//  * scores not carried in sort words: rank-side score = ds_bpermute pull
//    via sorted idx; pred-order g = ds_permute push to compacted slot
//    (R13 ballot+mbcnt logic, validated).
// Per 4 rows: DS = 6 shfl + 4 permute (2.5/row vs R13's 14); VALU ~200
// (sort 60, reduces 40). No LDS capacity use; ~48 VGPR -> full occupancy.
// Layout: lane 32h+e5 holds element e5 of rows {4g+h} (lo16/"A") and
// {4g+2+h} (hi16/"B"); loads coalesced: elem idx = 128g + lane (+64).

#define H 32
#define BLK 256
#define WPB 4

typedef unsigned short us2 __attribute__((ext_vector_type(2)));
union UP { uint32_t u; us2 v; };

template<int CTRL>
__device__ __forceinline__ uint32_t dppmov_u(uint32_t x) {
    return (uint32_t)__builtin_amdgcn_update_dpp(0, (int)x, CTRL, 0xF, 0xF, true);
}
template<int CTRL>
__device__ __forceinline__ float dppmov_f(float x) {
    return __int_as_float(
        __builtin_amdgcn_update_dpp(0, __float_as_int(x), CTRL, 0xF, 0xF, true));
}

// sum over each 32-lane half; lanes 31 and 63 hold their half's total
__device__ __forceinline__ float half_sum32(float v) {
    v += dppmov_f<0x111>(v);   // row_shr:1
    v += dppmov_f<0x112>(v);   // row_shr:2
    v += dppmov_f<0x114>(v);   // row_shr:4
    v += dppmov_f<0x118>(v);   // row_shr:8
    v += dppmov_f<0x142>(v);   // row_bcast:15 (rows 1,3 receive; 0-fill else)
    return v;
}

// packed u16 compare-exchange: per-half min/max, select whole dword by tm
__device__ __forceinline__ uint32_t cex(uint32_t W, uint32_t Wo, bool tm) {
    UP a, b, mn, mx;
    a.u = W; b.u = Wo;
    mn.v.x = a.v.x < b.v.x ? a.v.x : b.v.x;
    mx.v.x = a.v.x < b.v.x ? b.v.x : a.v.x;
    mn.v.y = a.v.y < b.v.y ? a.v.y : b.v.y;
    mx.v.y = a.v.y < b.v.y ? b.v.y : a.v.y;
    return tm ? mx.u : mn.u;
}

__global__ __launch_bounds__(BLK) void listwise_kernel(
    const float* __restrict__ scores,
    const int* __restrict__ rankings,
    const unsigned char* __restrict__ mask_u8,
    float* __restrict__ part_kl,
    float* __restrict__ part_cnt,
    int nrows, int ipw)
{
    __shared__ float s_kl[WPB], s_cnt[WPB];

    const int tid  = threadIdx.x;
    const int lane = tid & 63;
    const int wid  = tid >> 6;
    const int e5   = lane & 31;
    const int h    = lane >> 5;
    const uint32_t e5u = (uint32_t)e5;

    const long long wave_g  = (long long)blockIdx.x * WPB + wid;
    const long long tgroups = ((long long)nrows + 3) >> 2;   // 4 rows/group
    const long long gbeg = wave_g * ipw;
    const long long gend = (gbeg + ipw < tgroups) ? (gbeg + ipw) : tgroups;

    // mask dtype detect (bool=1B vs int32=4B); wave-uniform branch
    unsigned char probe = mask_u8[lane];
    const bool mask_is_i32 =
        (__ballot(((lane & 3) != 0) && (probe != 0)) == 0ull);

    float kl_acc = 0.0f, cnt_acc = 0.0f;

    if (gbeg < gend) {
        const size_t maxidx = (size_t)nrows * H - 1;

        // ---- prefetch group 0 (clamped; validity re-checked per row) ----
        size_t b0 = (size_t)gbeg * 128 + lane; if (b0 > maxidx) b0 = maxidx;
        size_t b1 = (size_t)gbeg * 128 + 64 + lane; if (b1 > maxidx) b1 = maxidx;
        int   rv0 = rankings[b0], rv1 = rankings[b1];
        float sv0 = scores[b0],   sv1 = scores[b1];
        uint32_t mm0, mm1;
        if (mask_is_i32) {
            mm0 = (uint32_t)((const int*)mask_u8)[b0];
            mm1 = (uint32_t)((const int*)mask_u8)[b1];
        } else {
            mm0 = (uint32_t)mask_u8[b0];
            mm1 = (uint32_t)mask_u8[b1];
        }

        for (long long g = gbeg; g < gend; ++g) {
            // ---- issue next-group loads (1-deep prefetch) ----
            const long long gn = (g + 1 < gend) ? (g + 1) : g;
            size_t nb0 = (size_t)gn * 128 + lane; if (nb0 > maxidx) nb0 = maxidx;
            size_t nb1 = (size_t)gn * 128 + 64 + lane; if (nb1 > maxidx) nb1 = maxidx;
            const int   xrv0 = rankings[nb0], xrv1 = rankings[nb1];
            const float xsv0 = scores[nb0],   xsv1 = scores[nb1];
            uint32_t xmm0, xmm1;
            if (mask_is_i32) {
                xmm0 = (uint32_t)((const int*)mask_u8)[nb0];
                xmm1 = (uint32_t)((const int*)mask_u8)[nb1];
            } else {
                xmm0 = (uint32_t)mask_u8[nb0];
                xmm1 = (uint32_t)mask_u8[nb1];
            }

            // ---- rows this lane serves: A = 4g+h, B = 4g+2+h ----
            const int rowA = (int)(4 * g) + h;
            const int rowB = rowA + 2;
            const bool vA = (rowA < nrows) && (mm0 != 0u) && (rv0 > 0);
            const bool vB = (rowB < nrows) && (mm1 != 0u) && (rv1 > 0);

            // bf16-rounded scores (consistent with rounds 1-13)
            const float sA = __uint_as_float(((__float_as_uint(sv0) + 0x8000u) >> 16) << 16);
            const float sB = __uint_as_float(((__float_as_uint(sv1) + 0x8000u) >> 16) << 16);

            // u16 keys: valid -> (r<<5)|idx (<=0x43F), invalid -> 0x8000|idx
            const uint32_t kA = vA ? (((uint32_t)rv0 << 5) | e5u) : (0x8000u | e5u);
            const uint32_t kB = vB ? (((uint32_t)rv1 << 5) | e5u) : (0x8000u | e5u);
            uint32_t W = kA | (kB << 16);

            // ---- idx-order compacted slots via ballot+mbcnt (per row) ----
            const unsigned long long bmA = __ballot(vA);
            const unsigned long long bmB = __ballot(vB);
            const uint32_t lo_pcA = __builtin_popcount((uint32_t)bmA);
            const uint32_t lo_pcB = __builtin_popcount((uint32_t)bmB);
            const uint32_t belowA = __builtin_amdgcn_mbcnt_hi(
                (uint32_t)(bmA >> 32),
                __builtin_amdgcn_mbcnt_lo((uint32_t)bmA, 0u));
            const uint32_t belowB = __builtin_amdgcn_mbcnt_hi(
                (uint32_t)(bmB >> 32),
                __builtin_amdgcn_mbcnt_lo((uint32_t)bmB, 0u));
            const int qA = (int)belowA - (h ? (int)lo_pcA : 0);
            const int qB = (int)belowB - (h ? (int)lo_pcB : 0);
            const int nvA = h ? __builtin_popcount((uint32_t)(bmA >> 32)) : (int)lo_pcA;
            const int nvB = h ? __builtin_popcount((uint32_t)(bmB >> 32)) : (int)lo_pcB;
            const int slotA = (vA ? qA : nvA + (e5 - qA)) + (h << 5);
            const int slotB = (vB ? qB : nvB + (e5 - qB)) + (h << 5);
            // push my idx-order score to its compacted position: lane p<nv
            // ends up holding g[p] (invalids parked at p>=nv, zeroed later)
            const float gA = __int_as_float(
                __builtin_amdgcn_ds_permute(slotA << 2, __float_as_int(sA)));
            const float gB = __int_as_float(
                __builtin_amdgcn_ds_permute(slotB << 2, __float_as_int(sB)));

            // ---- packed bitonic sort across each 32-lane half ----
            // j=1,2 exchanges: DPP quad_perm (VALU); j=4,8,16: shfl (DS)
            #pragma unroll
            for (int k = 2; k <= 32; k <<= 1) {
                #pragma unroll
                for (int j = k >> 1; j > 0; j >>= 1) {
                    uint32_t Wo;
                    if (j == 1)      Wo = dppmov_u<0xB1>(W);  // quad_perm[1,0,3,2]
                    else if (j == 2) Wo = dppmov_u<0x4E>(W);  // quad_perm[2,3,0,1]
                    else             Wo = (uint32_t)__shfl_xor((int)W, j);
                    const bool tm = (((e5 & j) == 0) != ((e5 & k) == 0));
                    W = cex(W, Wo, tm);
                }
            }

            // ---- rank-position p = e5: pull score via sorted idx ----
            const uint32_t WA = W & 0xFFFFu, WB = W >> 16;
            const bool vA2 = (WA & 0x8000u) == 0u;     // p < nvA
            const bool vB2 = (WB & 0x8000u) == 0u;
            const int iA = (int)(WA & 31u), iB = (int)(WB & 31u);
            const float srA = __int_as_float(__builtin_amdgcn_ds_bpermute(
                (((h << 5) | iA) << 2), __float_as_int(sA)));
            const float srB = __int_as_float(__builtin_amdgcn_ds_bpermute(
                (((h << 5) | iB) << 2), __float_as_int(sB)));

            float eA = __expf(srA); eA = vA2 ? eA : 0.0f;
            float eB = __expf(srB); eB = vB2 ? eB : 0.0f;
            const float tA = eA * (srA - gA);   // eA=0 kills junk g at p>=nv
            const float tB = eB * (srB - gB);

            // ---- DPP reductions (zero DS); lanes 31/63 hold half sums ----
            const float seA = half_sum32(eA);
            const float seB = half_sum32(eB);
            const float nmA = half_sum32(tA);
            const float nmB = half_sum32(tB);

            const float cA = (nvA > 1) ? __fdividef(nmA, seA) : 0.0f;
            const float cB = (nvB > 1) ? __fdividef(nmB, seB) : 0.0f;
            const bool tip = (e5 == 31);
            kl_acc  += tip ? (cA + cB) : 0.0f;
            cnt_acc += tip ? ((nvA > 1 ? 1.0f : 0.0f) + (nvB > 1 ? 1.0f : 0.0f))
                           : 0.0f;

            rv0 = xrv0; rv1 = xrv1; sv0 = xsv0; sv1 = xsv1;
            mm0 = xmm0; mm1 = xmm1;
        }
    }

    // ---- wave reduction (lanes 31/63 carry), then block partial ----
    #pragma unroll
    for (int m = 32; m >= 1; m >>= 1) {
        kl_acc  += __shfl_xor(kl_acc, m);
        cnt_acc += __shfl_xor(cnt_acc, m);
    }
    if (lane == 0) { s_kl[wid] = kl_acc; s_cnt[wid] = cnt_acc; }
    __syncthreads();
    if (tid == 0) {
        part_kl[blockIdx.x]  = s_kl[0] + s_kl[1] + s_kl[2] + s_kl[3];
        part_cnt[blockIdx.x] = s_cnt[0] + s_cnt[1] + s_cnt[2] + s_cnt[3];
    }
}

__global__ __launch_bounds__(256) void finalize_kernel(
    const float* __restrict__ part_kl,
    const float* __restrict__ part_cnt,
    float* __restrict__ out, int nblk)
{
    float k = 0.0f, c = 0.0f;
    for (int i = threadIdx.x; i < nblk; i += 256) {
        k += part_kl[i];
        c += part_cnt[i];
    }
    #pragma unroll
    for (int m = 32; m >= 1; m >>= 1) {
        k += __shfl_xor(k, m);
        c += __shfl_xor(c, m);
    }
    __shared__ float sk[4], sc[4];
    const int wid = threadIdx.x >> 6;
    if ((threadIdx.x & 63) == 0) { sk[wid] = k; sc[wid] = c; }
    __syncthreads();
    if (threadIdx.x == 0) {
        float K = sk[0] + sk[1] + sk[2] + sk[3];
        float C = sc[0] + sc[1] + sc[2] + sc[3];
        if (C < 1.0f) C = 1.0f;
        out[0] = K / C;
    }
}

extern "C" void kernel_launch(void* const* d_in, const int* in_sizes, int n_in,
                              void* d_out, int out_size, void* d_ws, size_t ws_size,
                              hipStream_t stream) {
    const float* scores = (const float*)d_in[0];
    const int* rankings = (const int*)d_in[1];
    const unsigned char* mask = (const unsigned char*)d_in[2];
    float* out = (float*)d_out;

    const int total = in_sizes[0];                 // B*H = 16777216
    const int nrows = total / H;                   // 524288 rows
    const int blocks = 2048;                       // 8192 waves, all resident
    const long long tgroups = ((long long)nrows + 3) >> 2;      // 131072
    const long long waves = (long long)blocks * WPB;            // 8192
    int ipw = (int)((tgroups + waves - 1) / waves);             // 16
    if (ipw < 1) ipw = 1;

    float* part_kl  = (float*)d_ws;               // [0, blocks)
    float* part_cnt = (float*)d_ws + blocks;      // [blocks, 2*blocks)

    listwise_kernel<<<blocks, BLK, 0, stream>>>(
        scores, rankings, mask, part_kl, part_cnt, nrows, ipw);

    finalize_kernel<<<1, 256, 0, stream>>>(part_kl, part_cnt, out, blocks);
}